// Round 7
// baseline (300.765 us; speedup 1.0000x reference)
//
#include <hip/hip_runtime.h>
#include <hip/hip_bf16.h>

// Problem constants
#define N_ROWS 8192
#define D_DIM  1024
#define HALF_N 4096
constexpr float INV_T = 1.0f / 0.07f;   // 14.2857143 — also the fixed softmax max M

typedef __attribute__((ext_vector_type(8))) short short8;  // 8 bf16 (4 VGPRs)
typedef __attribute__((ext_vector_type(4))) float f32x4;

__device__ __forceinline__ unsigned short f2bf(float x) {
    __hip_bfloat16 h = __float2bfloat16(x);
    return *reinterpret_cast<unsigned short*>(&h);
}

// async global->LDS, 16B/lane. LDS dest is wave-uniform base + lane*16.
__device__ __forceinline__ void async_ld16(const void* g, void* lds) {
    __builtin_amdgcn_global_load_lds(
        (const __attribute__((address_space(1))) void*)g,
        (__attribute__((address_space(3))) void*)lds,
        16, 0, 0);
}

// ---------------------------------------------------------------------------
// Kernel 1: row norms + bf16 normalized copy + fp32-exact target similarity
// + row_sum zeroing. One wave per row; pair row (i+4096 mod 8192) is read
// again here (L3-resident) to avoid a separate target kernel.
__global__ __launch_bounds__(256) void norm_kernel(const float* __restrict__ feat,
                                                   unsigned short* __restrict__ fn,
                                                   float* __restrict__ row_sum,
                                                   float* __restrict__ s_target) {
    const int w = threadIdx.x >> 6, lane = threadIdx.x & 63;
    const int row = blockIdx.x * 4 + w;
    const int pair = (row + HALF_N) & (N_ROWS - 1);
    const float4* src = (const float4*)(feat + (size_t)row * D_DIM);
    const float4* psrc = (const float4*)(feat + (size_t)pair * D_DIM);
    float4 v[4];
    float ss = 0.f, sp = 0.f, dp = 0.f;
#pragma unroll
    for (int t = 0; t < 4; ++t) {
        v[t] = src[lane + 64 * t];
        float4 p = psrc[lane + 64 * t];
        ss += v[t].x * v[t].x + v[t].y * v[t].y + v[t].z * v[t].z + v[t].w * v[t].w;
        sp += p.x * p.x + p.y * p.y + p.z * p.z + p.w * p.w;
        dp += v[t].x * p.x + v[t].y * p.y + v[t].z * p.z + v[t].w * p.w;
    }
#pragma unroll
    for (int off = 32; off; off >>= 1) {
        ss += __shfl_xor(ss, off);
        sp += __shfl_xor(sp, off);
        dp += __shfl_xor(dp, off);
    }
    float nrm = fmaxf(sqrtf(ss), 1e-8f);
    if (lane == 0) {
        row_sum[row] = 0.f;
        s_target[row] = dp / (nrm * fmaxf(sqrtf(sp), 1e-8f)) * INV_T;
    }
    const float inv = 1.0f / nrm;
    ushort4* dst = (ushort4*)(fn + (size_t)row * D_DIM);
#pragma unroll
    for (int t = 0; t < 4; ++t) {
        ushort4 o;
        o.x = f2bf(v[t].x * inv);
        o.y = f2bf(v[t].y * inv);
        o.z = f2bf(v[t].z * inv);
        o.w = f2bf(v[t].w * inv);
        dst[lane + 64 * t] = o;
    }
}

// ---------------------------------------------------------------------------
// Kernel 2: flash-style sim GEMM (NT, A=B=fn) + fixed-max exp accumulation.
// Round-6 base (BK=32, rotate-within-row swizzle: conflict-free LDS + coalesced
// staging quads + lean registers, all verified) + DOUBLE-BUFFERED LDS:
// one barrier per kt; prefetch of kt+1 is issued before compute(kt), so the
// vmcnt drain at the next barrier pays (latency - compute) instead of full
// latency. The last k-step of each ct stages the NEXT ct's kt=0, overlapping
// the exp epilogue with staging. Buffer select is a compile-time +-4096
// element offset: no extra registers (rounds 2/3 showed in-loop dynamic
// address math costs ~90 VGPR and a wave/SIMD).
__global__ __launch_bounds__(256) void simgemm_kernel(const unsigned short* __restrict__ fn,
                                                      float* __restrict__ row_sum) {
    __shared__ __align__(16) unsigned short As[2 * 128 * 32];   // 16 KiB (2 bufs)
    __shared__ __align__(16) unsigned short Bs[2 * 128 * 32];   // 16 KiB
    const int tid = threadIdx.x;
    const int w = tid >> 6, lane = tid & 63;
    const int q = lane >> 4, c16 = lane & 15;
    const int r0 = blockIdx.y * 128;
    const int cg0 = blockIdx.x * 512;
    const int wr = (w >> 1) * 64;  // wave's row base within tile
    const int wc = (w & 1) * 64;   // wave's col base within tile
    const int wr4 = (w >> 1) * 4;  // wave's A chunk base (16-row chunks)
    const int wc4 = (w & 1) * 4;   // wave's B chunk base
    // staging: wave w stages chunks 2w, 2w+1 (rows w*32 .. w*32+31).
    const int srow = lane >> 2;                              // row within chunk
    const int skoff = ((lane & 3) ^ ((lane >> 3) & 3)) * 8;  // swizzled unit elem offset
    const int lds_w0 = (w * 2 + 0) * 512;
    const int lds_w1 = (w * 2 + 1) * 512;
    // fragment read element offset within a chunk (kt/ct-invariant):
    const int loff = c16 * 32 + (q ^ ((c16 >> 1) & 3)) * 8;

    const unsigned short* pa0 = fn + (size_t)(r0 + w * 32 + srow) * D_DIM + skoff;
    const unsigned short* pa1 = pa0 + 16 * D_DIM;

    float rs[4][4];                      // per-(row-subtile, reg) partial exp-sums
#pragma unroll
    for (int i = 0; i < 4; ++i)
#pragma unroll
        for (int r = 0; r < 4; ++r) rs[i][r] = 0.f;

    // prologue: stage ct=0, kt=0 into buffer 0
    {
        const unsigned short* b0 = fn + (size_t)(cg0 + w * 32 + srow) * D_DIM + skoff;
        async_ld16(pa0, (void*)&As[lds_w0]);
        async_ld16(pa1, (void*)&As[lds_w1]);
        async_ld16(b0, (void*)&Bs[lds_w0]);
        async_ld16(b0 + 16 * D_DIM, (void*)&Bs[lds_w1]);
    }

    for (int ct = 0; ct < 4; ++ct) {
        const int c0 = cg0 + ct * 128;
        // staging pointers for kt = 1..31 of this ct
        const unsigned short* qa0 = pa0 + 32;
        const unsigned short* qa1 = pa1 + 32;
        const unsigned short* pb0 = fn + (size_t)(c0 + w * 32 + srow) * D_DIM + skoff + 32;
        const unsigned short* pb1 = pb0 + 16 * D_DIM;

        f32x4 acc[4][4];
#pragma unroll
        for (int i = 0; i < 4; ++i)
#pragma unroll
            for (int j = 0; j < 4; ++j) acc[i][j] = (f32x4){0.f, 0.f, 0.f, 0.f};

        // kt = 0..29 in pairs; buffers ping-pong (even kt in buf0, odd in buf1)
        for (int kt2 = 0; kt2 < 15; ++kt2) {
            __syncthreads();  // buf0 staging visible; buf1 reads of kt-1 done
            // prefetch kt = 2*kt2+1 -> buf1
            async_ld16(qa0, (void*)&As[4096 + lds_w0]);
            async_ld16(qa1, (void*)&As[4096 + lds_w1]);
            async_ld16(pb0, (void*)&Bs[4096 + lds_w0]);
            async_ld16(pb1, (void*)&Bs[4096 + lds_w1]);
            qa0 += 32; qa1 += 32; pb0 += 32; pb1 += 32;
            {   // compute kt = 2*kt2 from buf0
                short8 af[4], bf[4];
#pragma unroll
                for (int i = 0; i < 4; ++i)
                    af[i] = *(const short8*)&As[(wr4 + i) * 512 + loff];
#pragma unroll
                for (int j = 0; j < 4; ++j)
                    bf[j] = *(const short8*)&Bs[(wc4 + j) * 512 + loff];
#pragma unroll
                for (int i = 0; i < 4; ++i)
#pragma unroll
                    for (int j = 0; j < 4; ++j)
                        acc[i][j] = __builtin_amdgcn_mfma_f32_16x16x32_bf16(af[i], bf[j], acc[i][j], 0, 0, 0);
            }
            __syncthreads();  // buf1 staging visible; buf0 reads done
            // prefetch kt = 2*kt2+2 -> buf0
            async_ld16(qa0, (void*)&As[lds_w0]);
            async_ld16(qa1, (void*)&As[lds_w1]);
            async_ld16(pb0, (void*)&Bs[lds_w0]);
            async_ld16(pb1, (void*)&Bs[lds_w1]);
            qa0 += 32; qa1 += 32; pb0 += 32; pb1 += 32;
            {   // compute kt = 2*kt2+1 from buf1
                short8 af[4], bf[4];
#pragma unroll
                for (int i = 0; i < 4; ++i)
                    af[i] = *(const short8*)&As[4096 + (wr4 + i) * 512 + loff];
#pragma unroll
                for (int j = 0; j < 4; ++j)
                    bf[j] = *(const short8*)&Bs[4096 + (wc4 + j) * 512 + loff];
#pragma unroll
                for (int i = 0; i < 4; ++i)
#pragma unroll
                    for (int j = 0; j < 4; ++j)
                        acc[i][j] = __builtin_amdgcn_mfma_f32_16x16x32_bf16(af[i], bf[j], acc[i][j], 0, 0, 0);
            }
        }

        // peeled kt = 30, 31
        __syncthreads();
        // prefetch kt = 31 -> buf1
        async_ld16(qa0, (void*)&As[4096 + lds_w0]);
        async_ld16(qa1, (void*)&As[4096 + lds_w1]);
        async_ld16(pb0, (void*)&Bs[4096 + lds_w0]);
        async_ld16(pb1, (void*)&Bs[4096 + lds_w1]);
        {   // compute kt = 30 from buf0
            short8 af[4], bf[4];
#pragma unroll
            for (int i = 0; i < 4; ++i)
                af[i] = *(const short8*)&As[(wr4 + i) * 512 + loff];
#pragma unroll
            for (int j = 0; j < 4; ++j)
                bf[j] = *(const short8*)&Bs[(wc4 + j) * 512 + loff];
#pragma unroll
            for (int i = 0; i < 4; ++i)
#pragma unroll
                for (int j = 0; j < 4; ++j)
                    acc[i][j] = __builtin_amdgcn_mfma_f32_16x16x32_bf16(af[i], bf[j], acc[i][j], 0, 0, 0);
        }
        __syncthreads();
        if (ct < 3) {
            // stage next ct's kt=0 -> buf0 (overlaps kt=31 compute + epilogue)
            const unsigned short* nb0 = fn + (size_t)(c0 + 128 + w * 32 + srow) * D_DIM + skoff;
            async_ld16(pa0, (void*)&As[lds_w0]);
            async_ld16(pa1, (void*)&As[lds_w1]);
            async_ld16(nb0, (void*)&Bs[lds_w0]);
            async_ld16(nb0 + 16 * D_DIM, (void*)&Bs[lds_w1]);
        }
        {   // compute kt = 31 from buf1
            short8 af[4], bf[4];
#pragma unroll
            for (int i = 0; i < 4; ++i)
                af[i] = *(const short8*)&As[4096 + (wr4 + i) * 512 + loff];
#pragma unroll
            for (int j = 0; j < 4; ++j)
                bf[j] = *(const short8*)&Bs[4096 + (wc4 + j) * 512 + loff];
#pragma unroll
            for (int i = 0; i < 4; ++i)
#pragma unroll
                for (int j = 0; j < 4; ++j)
                    acc[i][j] = __builtin_amdgcn_mfma_f32_16x16x32_bf16(af[i], bf[j], acc[i][j], 0, 0, 0);
        }

        // epilogue: exp(sim - M), diag masked, accumulate per-row
#pragma unroll
        for (int i = 0; i < 4; ++i) {
            const int growb = r0 + wr + i * 16 + q * 4;
#pragma unroll
            for (int r = 0; r < 4; ++r) {
                float s = 0.f;
#pragma unroll
                for (int j = 0; j < 4; ++j) {
                    const int gcol = c0 + wc + j * 16 + c16;
                    float sim = acc[i][j][r] * INV_T;
                    float e = __expf(sim - INV_T);
                    if (growb + r == gcol) e = 0.f;  // diagonal mask
                    s += e;
                }
                rs[i][r] += s;
            }
        }
    }

    // reduce across the 16 col-lanes of each quad, one atomic per row
#pragma unroll
    for (int i = 0; i < 4; ++i)
#pragma unroll
        for (int r = 0; r < 4; ++r) {
            float s = rs[i][r];
            s += __shfl_xor(s, 1);
            s += __shfl_xor(s, 2);
            s += __shfl_xor(s, 4);
            s += __shfl_xor(s, 8);
            if (c16 == 0) atomicAdd(&row_sum[r0 + wr + i * 16 + q * 4 + r], s);
        }
}

// ---------------------------------------------------------------------------
// Kernel 3: loss = mean_i [ M + log(row_sum_i) - s_target_i ]
__global__ __launch_bounds__(256) void loss_kernel(const float* __restrict__ row_sum,
                                                   const float* __restrict__ s_target,
                                                   float* __restrict__ out) {
    float local = 0.f;
    for (int i = threadIdx.x; i < N_ROWS; i += 256)
        local += (INV_T + __logf(row_sum[i])) - s_target[i];
#pragma unroll
    for (int off = 32; off; off >>= 1) local += __shfl_xor(local, off);
    __shared__ float part[4];
    if ((threadIdx.x & 63) == 0) part[threadIdx.x >> 6] = local;
    __syncthreads();
    if (threadIdx.x == 0)
        out[0] = (part[0] + part[1] + part[2] + part[3]) * (1.0f / N_ROWS);
}

// ---------------------------------------------------------------------------
extern "C" void kernel_launch(void* const* d_in, const int* in_sizes, int n_in,
                              void* d_out, int out_size, void* d_ws, size_t ws_size,
                              hipStream_t stream) {
    const float* feat = (const float*)d_in[0];
    float* out = (float*)d_out;
    char* ws = (char*)d_ws;

    unsigned short* fn = (unsigned short*)ws;                 // 8192*1024 bf16 = 16 MiB
    size_t off = (size_t)N_ROWS * D_DIM * sizeof(unsigned short);
    float* row_sum = (float*)(ws + off);  off += N_ROWS * sizeof(float);
    float* s_target = (float*)(ws + off);

    norm_kernel<<<N_ROWS / 4, 256, 0, stream>>>(feat, fn, row_sum, s_target);
    simgemm_kernel<<<dim3(16, 64), 256, 0, stream>>>(fn, row_sum);
    loss_kernel<<<1, 256, 0, stream>>>(row_sum, s_target, out);
}

// Round 8
// 180.683 us; speedup vs baseline: 1.6646x; 1.6646x over previous
//
#include <hip/hip_runtime.h>
#include <hip/hip_bf16.h>

// Problem constants
#define N_ROWS 8192
#define D_DIM  1024
#define HALF_N 4096
constexpr float INV_T = 1.0f / 0.07f;   // 14.2857143 — also the fixed softmax max M

typedef __attribute__((ext_vector_type(8))) short short8;  // 8 bf16 (4 VGPRs)
typedef __attribute__((ext_vector_type(4))) float f32x4;

__device__ __forceinline__ unsigned short f2bf(float x) {
    __hip_bfloat16 h = __float2bfloat16(x);
    return *reinterpret_cast<unsigned short*>(&h);
}

// async global->LDS, 16B/lane. LDS dest is wave-uniform base + lane*16.
__device__ __forceinline__ void async_ld16(const void* g, void* lds) {
    __builtin_amdgcn_global_load_lds(
        (const __attribute__((address_space(1))) void*)g,
        (__attribute__((address_space(3))) void*)lds,
        16, 0, 0);
}

// ---------------------------------------------------------------------------
// Kernel 1: row norms + bf16 normalized copy + row_sum zeroing. One wave/row.
// (s_target is now extracted inside the GEMM from tile-pairs (I, I+32).)
__global__ __launch_bounds__(256) void norm_kernel(const float* __restrict__ feat,
                                                   unsigned short* __restrict__ fn,
                                                   float* __restrict__ row_sum) {
    const int w = threadIdx.x >> 6, lane = threadIdx.x & 63;
    const int row = blockIdx.x * 4 + w;
    const float4* src = (const float4*)(feat + (size_t)row * D_DIM);
    float4 v[4];
    float ss = 0.f;
#pragma unroll
    for (int t = 0; t < 4; ++t) {
        v[t] = src[lane + 64 * t];
        ss += v[t].x * v[t].x + v[t].y * v[t].y + v[t].z * v[t].z + v[t].w * v[t].w;
    }
#pragma unroll
    for (int off = 32; off; off >>= 1) ss += __shfl_xor(ss, off);
    float nrm = fmaxf(sqrtf(ss), 1e-8f);
    if (lane == 0) row_sum[row] = 0.f;
    const float inv = 1.0f / nrm;
    ushort4* dst = (ushort4*)(fn + (size_t)row * D_DIM);
#pragma unroll
    for (int t = 0; t < 4; ++t) {
        ushort4 o;
        o.x = f2bf(v[t].x * inv);
        o.y = f2bf(v[t].y * inv);
        o.z = f2bf(v[t].z * inv);
        o.w = f2bf(v[t].w * inv);
        dst[lane + 64 * t] = o;
    }
}

// ---------------------------------------------------------------------------
// Kernel 2: SYMMETRIC flash-style sim GEMM + fixed-max exp accumulation.
// sim = fn.fn^T is symmetric: only the 64*65/2 = 2080 upper-triangular
// 128x128 tile pairs (I<=J) are computed (half the FLOPs/staging of round 6).
// Epilogue adds exp(sim-M) to row sums (rows in I) AND, for I<J, to column
// sums (= symmetric row sums for rows in J, via 4 extra atomics/wave).
// Diagonal tiles count once with the diag mask. s_target = sim[i, i+4096]
// is extracted in tile-pairs with J == I+32 (plus the symmetric write).
// K-loop = round 6's proven structure: BK=32, 2 barriers/kt,
// rotate-within-row swizzle (conflict-free LDS + coalesced staging quads,
// SQ_LDS_BANK_CONFLICT=0, 112 VGPR). No dbuf (round 7: +17% regression),
// no min-waves clause (round 4: spills).
__global__ __launch_bounds__(256) void simgemm_kernel(const unsigned short* __restrict__ fn,
                                                      float* __restrict__ row_sum,
                                                      float* __restrict__ s_target) {
    __shared__ __align__(16) unsigned short As[128 * 32];   // 8 KiB
    __shared__ __align__(16) unsigned short Bs[128 * 32];   // 8 KiB
    // triangular decode: t -> (a,b), b<=a; I=b (row tile), J=a (col tile)
    const int t = blockIdx.x;
    int a = (int)((sqrtf(8.f * (float)t + 1.f) - 1.f) * 0.5f);
    while ((a + 1) * (a + 2) / 2 <= t) ++a;
    while (a * (a + 1) / 2 > t) --a;
    const int I = t - a * (a + 1) / 2;   // row-tile index (<= J)
    const int J = a;                     // col-tile index
    const int r0 = I * 128, c0 = J * 128;
    const bool isdiag = (I == J);
    const bool haspair = (J == I + 32);  // contains sim[i, i+4096] for rows in I

    const int tid = threadIdx.x;
    const int w = tid >> 6, lane = tid & 63;
    const int q = lane >> 4, c16 = lane & 15;
    const int wr = (w >> 1) * 64;  // wave's row base within tile
    const int wc = (w & 1) * 64;   // wave's col base within tile
    const int wr4 = (w >> 1) * 4;  // wave's A chunk base (16-row chunks)
    const int wc4 = (w & 1) * 4;   // wave's B chunk base
    // staging: wave w stages chunks 2w, 2w+1 (rows w*32 .. w*32+31).
    const int srow = lane >> 2;                              // row within chunk
    const int skoff = ((lane & 3) ^ ((lane >> 3) & 3)) * 8;  // swizzled unit elem offset
    // fragment read element offset within a chunk (kt-invariant):
    const int loff = c16 * 32 + (q ^ ((c16 >> 1) & 3)) * 8;

    const unsigned short* pa0 = fn + (size_t)(r0 + w * 32 + srow) * D_DIM + skoff;
    const unsigned short* pa1 = pa0 + 16 * D_DIM;
    const unsigned short* pb0 = fn + (size_t)(c0 + w * 32 + srow) * D_DIM + skoff;
    const unsigned short* pb1 = pb0 + 16 * D_DIM;

    f32x4 acc[4][4];
#pragma unroll
    for (int i = 0; i < 4; ++i)
#pragma unroll
        for (int j = 0; j < 4; ++j) acc[i][j] = (f32x4){0.f, 0.f, 0.f, 0.f};

    for (int kt = 0; kt < 32; ++kt) {
        __syncthreads();  // previous k-step's reads done before overwrite
        async_ld16(pa0, (void*)&As[(w * 2 + 0) * 512]);
        async_ld16(pa1, (void*)&As[(w * 2 + 1) * 512]);
        async_ld16(pb0, (void*)&Bs[(w * 2 + 0) * 512]);
        async_ld16(pb1, (void*)&Bs[(w * 2 + 1) * 512]);
        pa0 += 32; pa1 += 32; pb0 += 32; pb1 += 32;
        __syncthreads();  // drains vmcnt(0): staging visible

        short8 af[4], bf[4];
#pragma unroll
        for (int i = 0; i < 4; ++i)
            af[i] = *(const short8*)&As[(wr4 + i) * 512 + loff];
#pragma unroll
        for (int j = 0; j < 4; ++j)
            bf[j] = *(const short8*)&Bs[(wc4 + j) * 512 + loff];
#pragma unroll
        for (int i = 0; i < 4; ++i)
#pragma unroll
            for (int j = 0; j < 4; ++j)
                acc[i][j] = __builtin_amdgcn_mfma_f32_16x16x32_bf16(af[i], bf[j], acc[i][j], 0, 0, 0);
    }

    // epilogue: e = exp(sim - M); rows-in-I sums + (I<J) cols-in-J sums.
    float cs[4] = {0.f, 0.f, 0.f, 0.f};   // per-j column partial sums
#pragma unroll
    for (int i = 0; i < 4; ++i) {
        const int growb = r0 + wr + i * 16 + q * 4;
#pragma unroll
        for (int r = 0; r < 4; ++r) {
            const int grow = growb + r;
            float s = 0.f;
#pragma unroll
            for (int j = 0; j < 4; ++j) {
                const int gcol = c0 + wc + j * 16 + c16;
                float sim = acc[i][j][r] * INV_T;
                float e = __expf(sim - INV_T);
                if (isdiag && grow == gcol) e = 0.f;   // diagonal mask
                if (haspair && gcol == grow + HALF_N) {
                    s_target[grow] = sim;              // label similarity
                    s_target[gcol] = sim;              // symmetric counterpart
                }
                s += e;
                cs[j] += e;
            }
            // row path: reduce over the 16 col-lanes of the quad
            s += __shfl_xor(s, 1);
            s += __shfl_xor(s, 2);
            s += __shfl_xor(s, 4);
            s += __shfl_xor(s, 8);
            if (c16 == 0) atomicAdd(&row_sum[grow], s);
        }
    }
    if (!isdiag) {
        // col path: reduce each cs[j] across the 4 quads (rows), then one
        // atomic per column from the q==0 lanes.
#pragma unroll
        for (int j = 0; j < 4; ++j) {
            float s = cs[j];
            s += __shfl_xor(s, 16);
            s += __shfl_xor(s, 32);
            if (q == 0) atomicAdd(&row_sum[c0 + wc + j * 16 + c16], s);
        }
    }
}

// ---------------------------------------------------------------------------
// Kernel 3: loss = mean_i [ M + log(row_sum_i) - s_target_i ]
__global__ __launch_bounds__(256) void loss_kernel(const float* __restrict__ row_sum,
                                                   const float* __restrict__ s_target,
                                                   float* __restrict__ out) {
    float local = 0.f;
    for (int i = threadIdx.x; i < N_ROWS; i += 256)
        local += (INV_T + __logf(row_sum[i])) - s_target[i];
#pragma unroll
    for (int off = 32; off; off >>= 1) local += __shfl_xor(local, off);
    __shared__ float part[4];
    if ((threadIdx.x & 63) == 0) part[threadIdx.x >> 6] = local;
    __syncthreads();
    if (threadIdx.x == 0)
        out[0] = (part[0] + part[1] + part[2] + part[3]) * (1.0f / N_ROWS);
}

// ---------------------------------------------------------------------------
extern "C" void kernel_launch(void* const* d_in, const int* in_sizes, int n_in,
                              void* d_out, int out_size, void* d_ws, size_t ws_size,
                              hipStream_t stream) {
    const float* feat = (const float*)d_in[0];
    float* out = (float*)d_out;
    char* ws = (char*)d_ws;

    unsigned short* fn = (unsigned short*)ws;                 // 8192*1024 bf16 = 16 MiB
    size_t off = (size_t)N_ROWS * D_DIM * sizeof(unsigned short);
    float* row_sum = (float*)(ws + off);  off += N_ROWS * sizeof(float);
    float* s_target = (float*)(ws + off);

    norm_kernel<<<N_ROWS / 4, 256, 0, stream>>>(feat, fn, row_sum);
    simgemm_kernel<<<2080, 256, 0, stream>>>(fn, row_sum, s_target);
    loss_kernel<<<1, 256, 0, stream>>>(row_sum, s_target, out);
}